// Round 10
// baseline (162.677 us; speedup 1.0000x reference)
//
#include <hip/hip_runtime.h>
#include <math.h>

#define NROWS 8192
#define HALF  4096
#define EMB   2048
#define DIM   256
#define INV_T 10.0f

typedef __bf16 bf16x8v __attribute__((ext_vector_type(8)));
typedef __bf16 bf16x4v __attribute__((ext_vector_type(4)));
typedef float  f32x4   __attribute__((ext_vector_type(4)));

__device__ __forceinline__ void gld_lds16(const void* g, void* l) {
    __builtin_amdgcn_global_load_lds((const __attribute__((address_space(1))) void*)g,
                                     (__attribute__((address_space(3))) void*)l,
                                     16, 0, 0);
}

// ---------- K0: W [2048][256] f32 -> Wt [256][2048] bf16, coalesced tile transpose ----------
__global__ __launch_bounds__(256) void wt_kernel(const float* __restrict__ W,
                                                 __bf16* __restrict__ Wt) {
    __shared__ __bf16 t[64][72];
    const int n0 = blockIdx.x * 64;
    const int k0 = blockIdx.y * 64;
    const int tid = threadIdx.x;
    const int c = tid & 63;
    const int rr = tid >> 6;
#pragma unroll
    for (int it = 0; it < 16; it++) {
        int k = it * 4 + rr;
        t[k][c] = (__bf16)W[(size_t)(k0 + k) * DIM + n0 + c];
    }
    __syncthreads();
#pragma unroll
    for (int it = 0; it < 16; it++) {
        int n = it * 4 + rr;
        Wt[(size_t)(n0 + n) * EMB + k0 + c] = t[c][n];
    }
}

// ---------- K1: head GEMM + bias + L2-norm, v10: WAVE-PRIVATE LDS RINGS, ZERO LOOP BARRIERS.
// Diagnosis: 7 head variants (41-50us) share one invariant -- block-wide barriers per
// K-iter; all pipes idle (Mfma 6%, VALU 6%, HBM 12%). Fix: each wave owns a private
// 24KB LDS ring (3 slots x [A 32rx32k f32 4KB | B 64c(own cols)x32k bf16 4KB]),
// staged only by global_load_lds + per-wave inline-asm vmcnt(16). vmcnt is per-wave,
// LDS region is per-wave => NO __syncthreads in the loop; every wave is an
// independent 16-load-deep pipeline (ring+vmcnt mechanics = v8, harness-validated).
// Cols split across waves (no B dup); A dup 4x hits L2. Norm fused in epilogue
// (2 barriers at end). K-order identical to all prior versions -> bitwise-same.
// A-swizzle: source granule g^((row&3)<<1), same XOR on read (2-way conflict = free).
#define HBK  32
#define HNIT (EMB / HBK)   // 64

__global__ __launch_bounds__(256) void head_fused(
    const float* __restrict__ A,      // [8192][2048] f32
    const __bf16* __restrict__ Wt,    // [256][2048] bf16
    const float* __restrict__ bias,   // [256] f32
    __bf16* __restrict__ outb)        // [8192][256] bf16 normalized
{
    __shared__ __align__(16) char smem[98304];   // 4 waves x 3 slots x 8KB
    __shared__ float red[32][4];
    __shared__ float inv_sh[32];

    const int tid  = threadIdx.x;
    const int wave = tid >> 6, lane = tid & 63;
    const int quad = lane >> 4, l15 = lane & 15;
    const int rowBase = blockIdx.x * 32;
    const int colBase = wave * 64;
    char* wbase = smem + wave * 24576;

    // ---- per-lane stage sources (wave-uniform linear LDS dests) ----
    // A chunk c (1KB = rows c*8..c*8+7): lane -> row c*8+(lane>>3), granule lane&7;
    // source granule pre-swizzled g ^ ((row&3)<<1)  (read applies same XOR).
    const float* aS[4];
#pragma unroll
    for (int c = 0; c < 4; c++) {
        const int rA = c * 8 + (lane >> 3);
        const int g  = lane & 7;
        aS[c] = A + (size_t)(rowBase + rA) * EMB + ((g ^ ((rA & 3) << 1)) << 2);
    }
    // B chunk j (1KB = cols j*16..j*16+15 of THIS wave's 64 cols): lane -> col
    // j*16+(lane>>2), granule lane&3 (16B = 8 bf16). No swizzle needed (8x8 optimal).
    const __bf16* bS[4];
#pragma unroll
    for (int j = 0; j < 4; j++) {
        const int cB = j * 16 + (lane >> 2);
        bS[j] = Wt + (size_t)(colBase + cB) * EMB + ((lane & 3) << 3);
    }

    f32x4 acc[2][4];
    const f32x4 zero = {0.f, 0.f, 0.f, 0.f};
#pragma unroll
    for (int m = 0; m < 2; m++)
#pragma unroll
        for (int n = 0; n < 4; n++) acc[m][n] = zero;

#define STG(s, kf) {                                   \
        char* sb_ = wbase + (s) * 8192;                \
        gld_lds16(aS[0] + (kf), sb_ + 0);              \
        gld_lds16(aS[1] + (kf), sb_ + 1024);           \
        gld_lds16(aS[2] + (kf), sb_ + 2048);           \
        gld_lds16(aS[3] + (kf), sb_ + 3072);           \
        gld_lds16(bS[0] + (kf), sb_ + 4096);           \
        gld_lds16(bS[1] + (kf), sb_ + 5120);           \
        gld_lds16(bS[2] + (kf), sb_ + 6144);           \
        gld_lds16(bS[3] + (kf), sb_ + 7168);           \
    }

#define CMP(s) {                                                                  \
        const char* sb_ = wbase + (s) * 8192;                                     \
        bf16x8v af_[2], bf_[4];                                                   \
        _Pragma("unroll")                                                         \
        for (int m = 0; m < 2; m++) {                                             \
            const int row_ = m * 16 + l15;                                        \
            const int g0_  = (quad << 1) ^ ((row_ & 3) << 1);                     \
            f32x4 v0_ = *(const f32x4*)(sb_ + row_ * 128 + g0_ * 16);             \
            f32x4 v1_ = *(const f32x4*)(sb_ + row_ * 128 + (g0_ ^ 1) * 16);       \
            _Pragma("unroll")                                                     \
            for (int i = 0; i < 4; i++) { af_[m][i] = (__bf16)v0_[i];             \
                                          af_[m][4 + i] = (__bf16)v1_[i]; }       \
        }                                                                         \
        _Pragma("unroll")                                                         \
        for (int n = 0; n < 4; n++)                                               \
            bf_[n] = *(const bf16x8v*)(sb_ + 4096 + (n * 16 + l15) * 64           \
                                       + quad * 16);                              \
        _Pragma("unroll")                                                         \
        for (int m = 0; m < 2; m++)                                               \
            _Pragma("unroll")                                                     \
            for (int n = 0; n < 4; n++)                                           \
                acc[m][n] = __builtin_amdgcn_mfma_f32_16x16x32_bf16(af_[m],       \
                                bf_[n], acc[m][n], 0, 0, 0);                      \
    }

#define PHASE(cur, nxt) {                                       \
        STG(nxt, kS); kS += HBK;                                \
        __builtin_amdgcn_sched_barrier(0);                      \
        asm volatile("s_waitcnt vmcnt(16)" ::: "memory");       \
        __builtin_amdgcn_sched_barrier(0);                      \
        CMP(cur);                                               \
    }

    // ---- prologue: stage k-tiles 0,1 (16 loads in flight) ----
    int kS = 0;
    STG(0, kS); kS += HBK;
    STG(1, kS); kS += HBK;

    // ---- main loop: t=0..61 each stages t+2; slots cycle 0,1,2 ----
    for (int i = 0; i < 60; i += 3) {
        PHASE(0, 2);
        PHASE(1, 0);
        PHASE(2, 1);
    }
    PHASE(0, 2);   // t=60, stages 62
    PHASE(1, 0);   // t=61, stages 63
    // t=62 (slot 2): stage(63) still in flight
    __builtin_amdgcn_sched_barrier(0);
    asm volatile("s_waitcnt vmcnt(8)" ::: "memory");
    __builtin_amdgcn_sched_barrier(0);
    CMP(2);
    // t=63 (slot 0): drain
    __builtin_amdgcn_sched_barrier(0);
    asm volatile("s_waitcnt vmcnt(0)" ::: "memory");
    __builtin_amdgcn_sched_barrier(0);
    CMP(0);

#undef PHASE
#undef CMP
#undef STG

    // ---- epilogue: bias + row L2-norm (cross-wave via LDS) + bf16 store ----
    float bv[4];
#pragma unroll
    for (int n = 0; n < 4; n++) bv[n] = bias[colBase + n * 16 + l15];

    float ss[2][4];
#pragma unroll
    for (int m = 0; m < 2; m++)
#pragma unroll
        for (int r = 0; r < 4; r++) {
            float s = 0.f;
#pragma unroll
            for (int n = 0; n < 4; n++) {
                float v = acc[m][n][r] + bv[n];
                s += v * v;
            }
            ss[m][r] = s;
        }
#pragma unroll
    for (int off = 1; off < 16; off <<= 1)
#pragma unroll
        for (int m = 0; m < 2; m++)
#pragma unroll
            for (int r = 0; r < 4; r++) ss[m][r] += __shfl_xor(ss[m][r], off, 64);
    if (l15 == 0) {
#pragma unroll
        for (int m = 0; m < 2; m++)
#pragma unroll
            for (int r = 0; r < 4; r++) red[m * 16 + quad * 4 + r][wave] = ss[m][r];
    }
    __syncthreads();
    if (tid < 32) {
        float s = red[tid][0] + red[tid][1] + red[tid][2] + red[tid][3];
        inv_sh[tid] = 1.f / fmaxf(sqrtf(s), 1e-12f);
    }
    __syncthreads();
#pragma unroll
    for (int m = 0; m < 2; m++)
#pragma unroll
        for (int r = 0; r < 4; r++) {
            const int row = m * 16 + quad * 4 + r;
            const float iv = inv_sh[row];
#pragma unroll
            for (int n = 0; n < 4; n++) {
                float v = acc[m][n][r] + bv[n];
                outb[(size_t)(rowBase + row) * DIM + colBase + n * 16 + l15] =
                    (__bf16)(v * iv);
            }
        }
}

// ---------- K2: sim = X@X^T. (R6 version: 32 KB LDS -> 3 blocks/CU,
//              XOR-swizzled staging, shuffle-free unique-writer LDS epilogue, upper-tri grid) ----------
#define TILE 128
#define NTILE (NROWS / TILE)              // 64
#define NBLK  (NTILE * (NTILE + 1) / 2)   // 2080

__global__ __launch_bounds__(256, 3) void sim_kernel(
    const __bf16* __restrict__ X,
    float* __restrict__ total,
    float* __restrict__ posv)
{
    __shared__ __align__(16) char smem[32768];
    __bf16* a_base = (__bf16*)smem;            // [2][128][32]
    __bf16* b_base = (__bf16*)(smem + 16384);  // [2][128][32]
    float*  rs     = (float*)smem;             // [128][2][16] = 16 KB
    float*  cs     = (float*)(smem + 16384);   // [128][2][4]  = 4 KB

    const int t = blockIdx.x;
    int bx = (int)((129.0 - sqrt(16641.0 - 8.0 * (double)t)) * 0.5);
    while (64 * (bx + 1) - ((bx + 1) * bx) / 2 <= t) bx++;
    while (64 * bx - (bx * (bx - 1)) / 2 > t) bx--;
    const int by = bx + (t - (64 * bx - (bx * (bx - 1)) / 2));
    const bool diag = (bx == by);

    const int tid  = threadIdx.x;
    const int wave = tid >> 6, lane = tid & 63;
    const int quad = lane >> 4, l15 = lane & 15;
    const int rowBase = bx * TILE;
    const int colBase = by * TILE;
    const int waveRow = (wave >> 1) * 64;
    const int waveCol = (wave & 1) * 64;

    f32x4 acc[4][4];
    const f32x4 zero = {0.f, 0.f, 0.f, 0.f};
#pragma unroll
    for (int m = 0; m < 4; m++)
#pragma unroll
        for (int n = 0; n < 4; n++) acc[m][n] = zero;

    const int r16 = lane >> 2;
    const int b4  = lane & 3;
    const int sw  = (r16 >> 1) & 3;   // stage-side swizzle
    const int sr  = (l15 >> 1) & 3;   // read-side swizzle

    for (int k0 = 0; k0 < DIM; k0 += 64) {
        __syncthreads();
#pragma unroll
        for (int c = 0; c < 2; c++) {
#pragma unroll
            for (int j = 0; j < 2; j++) {
                int rg = wave * 2 + j;   // row-group 0..7
                const __bf16* asrc = X + (size_t)(rowBase + rg * 16 + r16) * DIM + k0 + c * 32 + (b4 ^ sw) * 8;
                const __bf16* bsrc = X + (size_t)(colBase + rg * 16 + r16) * DIM + k0 + c * 32 + (b4 ^ sw) * 8;
                gld_lds16(asrc, a_base + (c * TILE + rg * 16) * 32);
                gld_lds16(bsrc, b_base + (c * TILE + rg * 16) * 32);
            }
        }
        __syncthreads();
#pragma unroll
        for (int ks = 0; ks < 2; ks++) {
            bf16x8v af[4], bfv[4];
#pragma unroll
            for (int m = 0; m < 4; m++)
                af[m] = *(const bf16x8v*)(a_base + (ks * TILE + waveRow + m * 16 + l15) * 32 + (quad ^ sr) * 8);
#pragma unroll
            for (int n = 0; n < 4; n++)
                bfv[n] = *(const bf16x8v*)(b_base + (ks * TILE + waveCol + n * 16 + l15) * 32 + (quad ^ sr) * 8);
#pragma unroll
            for (int m = 0; m < 4; m++)
#pragma unroll
                for (int n = 0; n < 4; n++)
                    acc[m][n] = __builtin_amdgcn_mfma_f32_16x16x32_bf16(af[m], bfv[n], acc[m][n], 0, 0, 0);
        }
    }

    float es[4][4];
    float ecol[4];
#pragma unroll
    for (int n = 0; n < 4; n++) ecol[n] = 0.f;
#pragma unroll
    for (int m = 0; m < 4; m++) {
#pragma unroll
        for (int r = 0; r < 4; r++) {
            int grow = rowBase + waveRow + m * 16 + quad * 4 + r;
            float e_acc = 0.f;
#pragma unroll
            for (int n = 0; n < 4; n++) {
                int gcol = colBase + waveCol + n * 16 + l15;
                float s = acc[m][n][r];
                if (gcol - grow == HALF) { posv[grow] = s; posv[gcol] = s; }
                float e = (gcol == grow) ? 0.f : __expf(s * INV_T);
                e_acc += e;
                ecol[n] += e;
            }
            es[m][r] = e_acc;
        }
    }

    __syncthreads();
    const int wc = wave & 1;
    const int wr = wave >> 1;
#pragma unroll
    for (int m = 0; m < 4; m++)
#pragma unroll
        for (int r = 0; r < 4; r++) {
            int lrow = waveRow + m * 16 + quad * 4 + r;
            rs[(lrow * 2 + wc) * 16 + l15] = es[m][r];
        }
    if (!diag) {
#pragma unroll
        for (int n = 0; n < 4; n++) {
            int lcol = waveCol + n * 16 + l15;
            cs[(lcol * 2 + wr) * 4 + quad] = ecol[n];
        }
    }
    __syncthreads();

    if (tid < TILE) {
        float rsum = 0.f;
#pragma unroll
        for (int i = 0; i < 32; i++) rsum += rs[tid * 32 + i];
        atomicAdd(&total[rowBase + tid], rsum);
        if (!diag) {
            float csum = 0.f;
#pragma unroll
            for (int i = 0; i < 8; i++) csum += cs[tid * 8 + i];
            atomicAdd(&total[colBase + tid], csum);
        }
    }
}

// ---------- K3: loss ----------
__global__ __launch_bounds__(256) void loss_kernel(
    const float* __restrict__ total, const float* __restrict__ posv,
    float* __restrict__ out)
{
    __shared__ float red[4];
    const int tid = threadIdx.x;
    const int i = blockIdx.x * 256 + tid;
    float s = posv[i] * INV_T - __logf(total[i]);
#pragma unroll
    for (int off = 1; off < 64; off <<= 1) s += __shfl_xor(s, off, 64);
    if ((tid & 63) == 0) red[tid >> 6] = s;
    __syncthreads();
    if (tid == 0) {
        float v = red[0] + red[1] + red[2] + red[3];
        atomicAdd(out, -v / (float)NROWS);
    }
}

extern "C" void kernel_launch(void* const* d_in, const int* in_sizes, int n_in,
                              void* d_out, int out_size, void* d_ws, size_t ws_size,
                              hipStream_t stream) {
    const float* emb  = (const float*)d_in[0];
    const float* W    = (const float*)d_in[1];
    const float* bias = (const float*)d_in[2];
    float* out = (float*)d_out;

    char* ws = (char*)d_ws;
    __bf16* outb  = (__bf16*)ws;                          // 4 MB
    __bf16* Wt    = (__bf16*)(ws + (4u << 20));           // 1 MB
    float*  total = (float*)(ws + (5u << 20));            // 32 KB
    float*  posv  = (float*)(ws + (5u << 20) + (32u << 10));

    hipMemsetAsync(total, 0, NROWS * sizeof(float), stream);
    hipMemsetAsync(out, 0, sizeof(float), stream);

    wt_kernel<<<dim3(DIM / 64, EMB / 64), 256, 0, stream>>>(W, Wt);
    head_fused<<<dim3(NROWS / 32), 256, 0, stream>>>(emb, Wt, bias, outb);
    sim_kernel<<<dim3(NBLK), 256, 0, stream>>>(outb, total, posv);
    loss_kernel<<<dim3(NROWS / 256), 256, 0, stream>>>(total, posv, out);
}